// Round 8
// baseline (3203.888 us; speedup 1.0000x reference)
//
#include <hip/hip_runtime.h>

#define BATCH 512
#define SEQL  512
#define NIN   128
#define NH    512
#define NOUT  128
#define PRED  32
#define NSTEP (SEQL + PRED)

#define G_B 8
#define G_H 32
#define BT  64
#define NWG (G_B * G_H)
#define NTHREADS 256

// LDS layout (shorts). Weights stored in MFMA-FRAGMENT order:
// frag (g, ks) base = (g*16+ks)*512 + lane*8  -> ds_read_b128 is perfectly
// linear per instruction (lane*16B), ZERO bank conflicts, no index math.
#define OFF_WIH  24576      // Whh frags: 3 gates * 16 ks * 64 lanes * 8
#define OFF_WOUT 30720      // Wih frags: 3 gates *  4 ks * 64 lanes * 8
#define OFF_TR   38912      // Wout frags: 16 ks * 64 lanes * 8
#define LDS_SH   40448      // + 4 waves * 384 transpose scratch

typedef short bf16x8 __attribute__((ext_vector_type(8)));
typedef float f32x4 __attribute__((ext_vector_type(4)));
typedef unsigned int u32x4 __attribute__((ext_vector_type(4)));

#define MFMA __builtin_amdgcn_mfma_f32_16x16x32_bf16

__device__ __forceinline__ unsigned short f2bf(float f) {
    unsigned int u = __float_as_uint(f);
    u = (u + 0x7fffu + ((u >> 16) & 1u)) >> 16;   // RTNE
    return (unsigned short)u;
}
__device__ __forceinline__ float sigm(float x) {
    x = fminf(fmaxf(x, -30.f), 30.f);
    return 1.f / (1.f + __expf(-x));
}
__device__ __forceinline__ float tanh_f(float x) {
    x = fminf(fmaxf(x, -15.f), 15.f);
    float e = __expf(2.f * x);
    return (e - 1.f) / (e + 1.f);
}

// Zero h0 and the per-wave flag words (8 bg * 4 waves * 32 hs = 1024 ints)
// with sc1 stores (land at the chip-coherent MALL point).
__global__ __launch_bounds__(256) void zero_kernel(unsigned short* hbuf, int* cnt)
{
    const int tid = threadIdx.x, wg = blockIdx.x;
    u32x4 z = {0, 0, 0, 0};
    char* base = (char*)hbuf + ((wg * 256 + tid) * 32);   // 64*256*32B = 512 KiB
    asm volatile("global_store_dwordx4 %0, %1, off sc1" :: "v"(base), "v"(z) : "memory");
    asm volatile("global_store_dwordx4 %0, %1, off offset:16 sc1" :: "v"(base), "v"(z) : "memory");
    if (wg == 0) {
        int zz = 0;
        asm volatile("global_store_dword %0, %1, off sc1" :: "v"(cnt + tid), "v"(zz) : "memory");
        asm volatile("global_store_dword %0, %1, off sc1" :: "v"(cnt + 256 + tid), "v"(zz) : "memory");
        asm volatile("global_store_dword %0, %1, off sc1" :: "v"(cnt + 512 + tid), "v"(zz) : "memory");
        asm volatile("global_store_dword %0, %1, off sc1" :: "v"(cnt + 768 + tid), "v"(zz) : "memory");
    }
}

// Persistent GRU kernel. WG (bg, hs): batch rows [bg*64,+64), units [hs*16,+16).
// WAVE-GRANULAR sync: wave w of (bg,hs) writes rows [bg*64+w*16,+16) of its 16
// units; it is read at t+1 ONLY by waves (bg, w, *). Per-wave flags
// flags[bg][w][hs]; no __syncthreads in the loop — each wave is an
// independent pipeline. Poll = single ballot load: 64 lanes each load one
// flag dword (one 128B transaction), __ballot(f>=target) decides.
// All data via sc1 (chip-coherent MALL point); zero cache maintenance ops.
__global__ __launch_bounds__(NTHREADS, 1) void gru_kernel(
    const float* __restrict__ z_seq, const float* __restrict__ W_ih,
    const float* __restrict__ W_hh, const float* __restrict__ b_ih,
    const float* __restrict__ b_hh, const float* __restrict__ W_out,
    const float* __restrict__ b_out, float* __restrict__ out,
    unsigned short* __restrict__ hbuf, int* __restrict__ cnt)
{
    __shared__ unsigned short s_w[LDS_SH];
    const int tid = threadIdx.x;
    const int wg  = blockIdx.x;
    const int bg  = wg & 7;
    const int hs  = wg >> 3;

    // ---- stage weights in fragment-linear order (fp32 -> bf16) ----
    for (int i = tid; i < 24576; i += NTHREADS) {
        int e = i & 7, ln = (i >> 3) & 63, ks = (i >> 9) & 15, g = i >> 13;
        int unit = hs * 16 + (ln & 15);
        int k = ks * 32 + (ln >> 4) * 8 + e;
        s_w[i] = f2bf(W_hh[(g * 512 + unit) * 512 + k]);
    }
    for (int i = tid; i < 6144; i += NTHREADS) {
        int e = i & 7, ln = (i >> 3) & 63, ks = (i >> 9) & 3, g = i >> 11;
        int unit = hs * 16 + (ln & 15);
        int k = ks * 32 + (ln >> 4) * 8 + e;
        s_w[OFF_WIH + i] = f2bf(W_ih[(g * 512 + unit) * 128 + k]);
    }
    for (int i = tid; i < 8192; i += NTHREADS) {
        int e = i & 7, ln = (i >> 3) & 63, ks = i >> 9;
        int ocol = hs * 4 + (ln & 3);           // cols duplicated x4
        int k = ks * 32 + (ln >> 4) * 8 + e;
        s_w[OFF_WOUT + i] = f2bf(W_out[ocol * 512 + k]);
    }
    __syncthreads();

    const int lane = tid & 63;
    const int wave = tid >> 6;
    const int li   = lane & 15;       // MFMA row-of-A / col-of-B / col-of-C
    const int kq   = lane >> 4;       // k-chunk selector
    const int jg   = hs * 16 + li;    // global hidden unit of this lane

    const float bihr = b_ih[jg], bihz = b_ih[NH + jg], bihn = b_ih[2 * NH + jg];
    const float bhhr = b_hh[jg], bhhz = b_hh[NH + jg], bhhn = b_hh[2 * NH + jg];
    const float bo   = b_out[hs * 4 + (li & 3)];

    const int aRow = bg * BT + wave * 16 + li;        // batch row for A frags
    const int cRow = bg * BT + wave * 16 + kq * 4;    // C rows (+q)
    float hreg[4] = {0.f, 0.f, 0.f, 0.f};             // fp32 h state in regs

    const unsigned short* fb = s_w + lane * 8;            // per-lane frag base
    unsigned short* tr = s_w + OFF_TR + wave * 384;       // transpose scratch

    // per-wave flags: flags[(bg*4 + w)*32 + hs]
    int* myFlag = cnt + ((bg * 4 + wave) << 5) + hs;
    const int* fp = cnt + ((bg * 4 + wave) << 5) + (lane & 31);  // poll addr
    int  dead  = 0;

    // ---- prologue: input-side pre-activations for t = 0 ----
    f32x4 ir = {0,0,0,0}, iz = {0,0,0,0}, in = {0,0,0,0};
    {
        const float* zrow = z_seq + ((long)aRow * SEQL + 0) * NIN + kq * 8;
#pragma unroll
        for (int ks = 0; ks < 4; ++ks) {
            float4 z0 = *(const float4*)(zrow + ks * 32);
            float4 z1 = *(const float4*)(zrow + ks * 32 + 4);
            union { bf16x8 v; unsigned short u[8]; } az;
            az.u[0] = f2bf(z0.x); az.u[1] = f2bf(z0.y);
            az.u[2] = f2bf(z0.z); az.u[3] = f2bf(z0.w);
            az.u[4] = f2bf(z1.x); az.u[5] = f2bf(z1.y);
            az.u[6] = f2bf(z1.z); az.u[7] = f2bf(z1.w);
            ir = MFMA(az.v, *(const bf16x8*)(fb + OFF_WIH + ks * 512), ir, 0, 0, 0);
            iz = MFMA(az.v, *(const bf16x8*)(fb + OFF_WIH + 2048 + ks * 512), iz, 0, 0, 0);
            in = MFMA(az.v, *(const bf16x8*)(fb + OFF_WIH + 4096 + ks * 512), in, 0, 0, 0);
        }
    }

    for (int t = 0; t <= NSTEP; ++t) {
        const unsigned short* hin  = hbuf + (t & 1) * (BATCH * NH);
        unsigned short*       hout = hbuf + ((t & 1) ^ 1) * (BATCH * NH);

        // A fragments: sc1 = agent-scope load from the MALL coherence point
        const unsigned short* hrow = hin + aRow * NH + kq * 8;
        bf16x8 a[16];
#pragma unroll
        for (int ks = 0; ks < 16; ++ks)
            asm volatile("global_load_dwordx4 %0, %1, off offset:%2 sc1"
                         : "=v"(a[ks]) : "v"(hrow), "i"(ks * 64) : "memory");
        asm volatile("s_waitcnt vmcnt(0)" ::: "memory");
        __builtin_amdgcn_sched_barrier(0);

        // decode: a[] holds h_t; y_td needs h_{SEQL+1+td} -> emit at t=SEQL+1+td
        if (t > SEQL) {
            int td = t - SEQL - 1;
            f32x4 y4 = {0, 0, 0, 0};
#pragma unroll
            for (int ks = 0; ks < 16; ++ks)
                y4 = MFMA(a[ks], *(const bf16x8*)(fb + OFF_WOUT + ks * 512), y4, 0, 0, 0);
            if (li < 4) {
#pragma unroll
                for (int q = 0; q < 4; ++q)
                    out[((long)(cRow + q) * PRED + td) * NOUT + hs * 4 + li] = y4[q] + bo;
            }
        }
        if (t == NSTEP) break;

        // hidden-side MFMA: fragment-linear B reads (zero bank conflicts)
        f32x4 hr = {0,0,0,0}, hz = {0,0,0,0}, hn = {0,0,0,0};
#pragma unroll
        for (int ks = 0; ks < 16; ++ks) {
            hr = MFMA(a[ks], *(const bf16x8*)(fb + ks * 512), hr, 0, 0, 0);
            hz = MFMA(a[ks], *(const bf16x8*)(fb + 8192 + ks * 512), hz, 0, 0, 0);
            hn = MFMA(a[ks], *(const bf16x8*)(fb + 16384 + ks * 512), hn, 0, 0, 0);
        }

        // gate math -> bf16 into per-wave LDS transpose tile (rows stride 24)
#pragma unroll
        for (int q = 0; q < 4; ++q) {
            float r  = sigm(bihr + ir[q] + bhhr + hr[q]);
            float zz = sigm(bihz + iz[q] + bhhz + hz[q]);
            float nn = tanh_f(bihn + in[q] + r * (bhhn + hn[q]));
            float hq = (1.f - zz) * nn + zz * hreg[q];
            hreg[q]  = hq;
            tr[(kq * 4 + q) * 24 + li] = f2bf(hq);
        }
        asm volatile("s_waitcnt lgkmcnt(0)" ::: "memory");
        __builtin_amdgcn_sched_barrier(0);

        // coalesced h store: 32 lanes x dwordx4 sc1 (16 rows x 2 chunks)
        if (lane < 32) {
            bf16x8 hv = *(const bf16x8*)(tr + (lane >> 1) * 24 + (lane & 1) * 8);
            int grow = bg * BT + wave * 16 + (lane >> 1);
            unsigned short* hp = hout + grow * NH + hs * 16 + (lane & 1) * 8;
            asm volatile("global_store_dwordx4 %0, %1, off sc1"
                         :: "v"(hp), "v"(hv) : "memory");
        }
        // wave-local drain, then signal THIS WAVE's flag (no __syncthreads)
        asm volatile("s_waitcnt vmcnt(0)" ::: "memory");
        if (lane == 0) {
            int v = t + 1;
            asm volatile("global_store_dword %0, %1, off sc1"
                         :: "v"(myFlag), "v"(v) : "memory");
        }

        // ---- barrier shadow: input-side pre-activations for t+1 ----
        f32x4 nir = {0,0,0,0}, niz = {0,0,0,0}, nin = {0,0,0,0};
        if (t + 1 < SEQL) {
            const float* zrow = z_seq + ((long)aRow * SEQL + (t + 1)) * NIN + kq * 8;
#pragma unroll
            for (int ks = 0; ks < 4; ++ks) {
                float4 z0 = *(const float4*)(zrow + ks * 32);
                float4 z1 = *(const float4*)(zrow + ks * 32 + 4);
                union { bf16x8 v; unsigned short u[8]; } az;
                az.u[0] = f2bf(z0.x); az.u[1] = f2bf(z0.y);
                az.u[2] = f2bf(z0.z); az.u[3] = f2bf(z0.w);
                az.u[4] = f2bf(z1.x); az.u[5] = f2bf(z1.y);
                az.u[6] = f2bf(z1.z); az.u[7] = f2bf(z1.w);
                nir = MFMA(az.v, *(const bf16x8*)(fb + OFF_WIH + ks * 512), nir, 0, 0, 0);
                niz = MFMA(az.v, *(const bf16x8*)(fb + OFF_WIH + 2048 + ks * 512), niz, 0, 0, 0);
                nin = MFMA(az.v, *(const bf16x8*)(fb + OFF_WIH + 4096 + ks * 512), nin, 0, 0, 0);
            }
        }

        // ---- ballot poll: each lane loads ONE flag dword (one 128B
        // transaction), wave proceeds when all 32 producers of its row block
        // have signaled t+1. No RMW, no min-tree, no syncthreads.
        const int target = t + 1;
        if (!dead) {
            int patience = 1000000;
            for (;;) {
                int f;
                asm volatile("global_load_dword %0, %1, off sc1\n\ts_waitcnt vmcnt(0)"
                             : "=v"(f) : "v"(fp) : "memory");
                if (__ballot(f >= target) == ~0ull) break;
                if (--patience == 0) { dead = 1; break; }
            }
        }
        __builtin_amdgcn_sched_barrier(0);

        ir = nir; iz = niz; in = nin;
    }
}

extern "C" void kernel_launch(void* const* d_in, const int* in_sizes, int n_in,
                              void* d_out, int out_size, void* d_ws, size_t ws_size,
                              hipStream_t stream)
{
    const float* z_seq = (const float*)d_in[0];
    const float* W_ih  = (const float*)d_in[1];
    const float* W_hh  = (const float*)d_in[2];
    const float* b_ih  = (const float*)d_in[3];
    const float* b_hh  = (const float*)d_in[4];
    const float* W_out = (const float*)d_in[5];
    const float* b_out = (const float*)d_in[6];
    float* out = (float*)d_out;

    unsigned short* hbuf = (unsigned short*)d_ws;                   // 2 x [512][512] bf16
    int* cnt = (int*)((char*)d_ws + (size_t)2 * BATCH * NH * 2);    // per-wave flags

    zero_kernel<<<dim3(64), dim3(256), 0, stream>>>(hbuf, cnt);
    gru_kernel<<<dim3(NWG), dim3(NTHREADS), 0, stream>>>(
        z_seq, W_ih, W_hh, b_ih, b_hh, W_out, b_out, out, hbuf, cnt);
}